// Round 5
// baseline (1833.942 us; speedup 1.0000x reference)
//
#include <hip/hip_runtime.h>

// Problem constants: T=2048, B=256, F=64, H=256, O=1
#define T_STEPS 2048
#define BATCH   256
#define FEAT    64
#define HID     256
#define KAUG    320   // FEAT + HID
#define NW      16    // 16 waves = 4 waves/SIMD (the R4 lesson: 1-2 waves/SIMD
#define NTHR    1024  //   starves the MFMA pipe at ~16.6 cyc/instr vs 4.85 ubench)
#define XTILE   16    // timesteps per x staging tile
#define NXB     4     // x-tile ring depth (write tile i+2 while reading tile i)
#define NTILES  (T_STEPS / XTILE)

typedef _Float16 half8 __attribute__((ext_vector_type(8)));
typedef float    f32x4 __attribute__((ext_vector_type(4)));
typedef float    f32x8 __attribute__((ext_vector_type(8)));

// fast tanh: tanh(z) = 1 - 2/(exp(2z)+1). Saturates correctly at +/-inf.
__device__ __forceinline__ float fast_tanh(float z) {
    float e = __expf(2.0f * z);
    return 1.0f - 2.0f * __builtin_amdgcn_rcpf(e + 1.0f);
}

// R5: R2 and R4 ran at IDENTICAL 1955 cyc/step despite opposite structures;
// common invariant = 40 MFMAs/SIMD at 1-2 waves/SIMD, and both show the same
// 16.6 cyc/MFMA effective rate (3.4x the 4.85-cyc high-occupancy ubench rate).
// Diagnosis: wave-starved MFMA issue + unoverlapped DS/epilogue glue.
// Fix: 16 thin waves (4/SIMD), constant MFMA work per SIMD:
//  - wave w owns N-tile w (neurons 16w..16w+15), all 10 K-chunks: 10 MFMAs,
//    B-frags = 10 half8 = 40 regs (MFMA-consumed -> AGPR-safe, R1 lesson).
//  - A-reads exec-masked to lanes {0,16,32,48} (R3/R4-proven correct).
//  - epilogue per wave: ONE tanh on lanes<16 (R4 had 4), 1 ds_write_b16.
//  - fc1: deferred one step (hides 4-shuffle chain), ONE LDS atomic per wave
//    (16/step; R2 ran 8/step fine, R3's regression was 4096/step).
//  - x staging zero-stall: xhold register carries tile i+3's data for 48
//    steps; LDS ring write of tile i+2 uses data loaded 16 steps ago ->
//    no vmcnt stall in any step (R2/R4 paid ~900 cyc every 16th step).
__global__
__attribute__((amdgpu_flat_work_group_size(NTHR, NTHR), amdgpu_waves_per_eu(4, 4)))
void rnn_kernel(const float* __restrict__ x,    // (T, B, F)
                const float* __restrict__ W0,   // (H, F+H) row-major
                const float* __restrict__ b0,   // (H)
                const float* __restrict__ Wfc,  // (1, H)
                const float* __restrict__ bfc,  // (1)
                float* __restrict__ out)        // (B, T)
{
    const int b    = blockIdx.x;
    const int tid  = threadIdx.x;
    const int w    = tid >> 6;
    const int lane = tid & 63;
    const int l15  = lane & 15;
    const int kg   = lane >> 4;          // k-group 0..3
    const bool alane = (l15 == 0);       // lanes 0,16,32,48: carry A-row 0

    __shared__ __align__(16) _Float16 h_buf[2][HID];            // 1 KB
    __shared__ __align__(16) _Float16 x_tile[NXB][XTILE][FEAT]; // 8 KB
    __shared__ __align__(16) float    out_buf[T_STEPS];         // 8 KB

    // ---- B-frags: wave w, N-tile w -> neuron n = 16w + l15; lane holds
    // W0[n][c*32 + kg*8 + e] as 8 f16. 10 frags = 40 regs/lane.
    half8 bw[10];
    {
        const float* wp = W0 + (16 * w + l15) * KAUG + kg * 8;
#pragma unroll
        for (int c = 0; c < 10; ++c) {
            const f32x8 v = *reinterpret_cast<const f32x8*>(wp + c * 32);
            bw[c] = __builtin_convertvector(v, half8);
        }
    }

    // epilogue constants (C-row 0 lives on lanes 0..15): neuron 16w + lane
    float b0e = 0.f, wfe = 0.f;
    if (lane < 16) {
        b0e = b0[16 * w + lane];
        wfe = Wfc[16 * w + lane];
    }
    const float bfc_r = bfc[0];

    // ---- prologue: h = 0, out_buf = bfc, stage x tiles 0,1; xhold = tile 2
    if (tid < HID) { h_buf[0][tid] = (_Float16)0.f; h_buf[1][tid] = (_Float16)0.f; }
    out_buf[tid]        = bfc_r;
    out_buf[tid + NTHR] = bfc_r;

    const int tr = tid >> 6;    // 0..15: timestep-row within tile
    const int fx = tid & 63;    // feature
#pragma unroll
    for (int ti = 0; ti < 2; ++ti) {
        const float v = x[(size_t)(XTILE * ti + tr) * (BATCH * FEAT) + b * FEAT + fx];
        x_tile[ti][tr][fx] = (_Float16)v;
    }
    float xhold = x[(size_t)(XTILE * 2 + tr) * (BATCH * FEAT) + b * FEAT + fx];
    __syncthreads();

    // A-frags persist: non-alane lanes keep zeros forever (they feed only
    // discarded C rows 1..15).
    half8 af[10];
#pragma unroll
    for (int c = 0; c < 10; ++c) af[c] = half8{};

    float p_prev = 0.f;   // deferred fc1 partial from step t-1 (lanes 0..15)
    const f32x4 zero4 = {0.f, 0.f, 0.f, 0.f};

    for (int t = 0; t < T_STEPS; ++t) {
        const int cur = t & 1;
        const int nxt = cur ^ 1;
        const int xb  = (t >> 4) & (NXB - 1);

        // ---- A-frag reads, exec-masked to 4 lanes/wave
        if (alane) {
            const _Float16* xr = &x_tile[xb][t & 15][kg * 8];
            af[0] = *reinterpret_cast<const half8*>(xr);
            af[1] = *reinterpret_cast<const half8*>(xr + 32);
            const _Float16* hr = &h_buf[cur][kg * 8];
#pragma unroll
            for (int c = 2; c < 10; ++c)
                af[c] = *reinterpret_cast<const half8*>(hr + (c - 2) * 32);
        }

        // ---- deferred fc1 reduce for step t-1 (hides under MFMA/DS latency)
        {
            float p = p_prev;
            p += __shfl_xor(p, 1, 64);
            p += __shfl_xor(p, 2, 64);
            p += __shfl_xor(p, 4, 64);
            p += __shfl_xor(p, 8, 64);
            if (lane == 0 && t > 0) atomicAdd(&out_buf[t - 1], p);
        }

        // ---- MFMA: 2 independent chains (even/odd chunks), depth 5.
        // x-chunks (0,1) first: independent of this step's h-read latency.
        f32x4 a0 = __builtin_amdgcn_mfma_f32_16x16x32_f16(af[0], bw[0], zero4, 0, 0, 0);
        f32x4 a1 = __builtin_amdgcn_mfma_f32_16x16x32_f16(af[1], bw[1], zero4, 0, 0, 0);
#pragma unroll
        for (int c = 2; c < 10; c += 2) {
            a0 = __builtin_amdgcn_mfma_f32_16x16x32_f16(af[c],     bw[c],     a0, 0, 0, 0);
            a1 = __builtin_amdgcn_mfma_f32_16x16x32_f16(af[c + 1], bw[c + 1], a1, 0, 0, 0);
        }

        // ---- x staging, zero-stall: ds_write uses xhold (loaded 16 steps
        // ago, vmcnt long satisfied); then issue the next tile's global load
        // (consumed 48 steps from now).
        if ((t & 15) == 0) {
            const int ti = t >> 4;
            if (ti + 2 < NTILES)
                x_tile[(ti + 2) & (NXB - 1)][tr][fx] = (_Float16)xhold;
            if (ti + 3 < NTILES)
                xhold = x[(size_t)(XTILE * (ti + 3) + tr) * (BATCH * FEAT) + b * FEAT + fx];
        }

        // ---- epilogue: C-row 0 = lanes 0..15, reg 0 (m89-verified layout)
        float pnew = 0.f;
        if (lane < 16) {
            const float h = fast_tanh(a0[0] + a1[0] + b0e);
            h_buf[nxt][16 * w + lane] = (_Float16)h;
            pnew = wfe * h;
        }
        p_prev = pnew;

        __syncthreads();   // h(t) + x_tile + out_buf[t-1] settled; 1 barrier/step
    }

    // tail: fc1 for the final step
    {
        float p = p_prev;
        p += __shfl_xor(p, 1, 64);
        p += __shfl_xor(p, 2, 64);
        p += __shfl_xor(p, 4, 64);
        p += __shfl_xor(p, 8, 64);
        if (lane == 0) atomicAdd(&out_buf[T_STEPS - 1], p);
    }
    __syncthreads();

    // ---- final epilogue: coalesced store of the block's 2048 outputs
    out[b * T_STEPS + tid]        = out_buf[tid];
    out[b * T_STEPS + tid + NTHR] = out_buf[tid + NTHR];
}

extern "C" void kernel_launch(void* const* d_in, const int* in_sizes, int n_in,
                              void* d_out, int out_size, void* d_ws, size_t ws_size,
                              hipStream_t stream) {
    const float* x   = (const float*)d_in[0];
    const float* W0  = (const float*)d_in[1];
    const float* b0  = (const float*)d_in[2];
    const float* Wfc = (const float*)d_in[3];
    const float* bfc = (const float*)d_in[4];
    // d_in[5] = feature_n == 0 -> no autoregressive tail
    float* out = (float*)d_out;

    rnn_kernel<<<dim3(BATCH), dim3(NTHR), 0, stream>>>(x, W0, b0, Wfc, bfc, out);
}